// Round 2
// baseline (270.294 us; speedup 1.0000x reference)
//
#include <hip/hip_runtime.h>

#define B_    2048
#define K_    32
#define D_    768
#define DICT_ 24576
#define C_    64

// One wave per item (b,i). item = b*K_ + i. 65536 waves total.
//   bias   = dot(up_enc[up_idx[item]], b_dec)                (all waves)
//   match  = ballot of conn[down_idx[item]][lane] vs up_idx  (all waves, uniform)
//   pairs  = dot(down_enc[di], up_dec[:, tgt]) per match     (~8% of waves)
// up_dec columns are read directly (strided); unique 64B lines ~= one pass
// over the matrix, served by shared L3 after first touch.
__global__ __launch_bounds__(256) void scae_fused_kernel(
        const float* __restrict__ up_vals,
        const float* __restrict__ up_dec,    // [D][DICT] row-major
        const float* __restrict__ down_enc,  // [DICT][D]
        const float* __restrict__ up_enc,    // [DICT][D]
        const float* __restrict__ b_dec,     // [D]
        const int*   __restrict__ up_idx,    // [B][K]
        const int*   __restrict__ down_idx,  // [B][K]
        const int*   __restrict__ conn,      // [DICT][C]
        float* __restrict__ out) {           // [B][K]
    const int wave = threadIdx.x >> 6;
    const int lane = threadIdx.x & 63;
    const int item = blockIdx.x * 4 + wave;
    const int b    = item >> 5;

    // ---- bias: dot(up_enc[ui], b_dec), distributed over lanes ----
    const int ui = up_idx[item];
    const float4* rp = (const float4*)(up_enc + (size_t)ui * D_);
    const float4* bp = (const float4*)b_dec;
    float acc = 0.f;
    #pragma unroll
    for (int ii = 0; ii < 3; ++ii) {
        float4 a  = rp[lane + 64 * ii];
        float4 bb = bp[lane + 64 * ii];
        acc += a.x * bb.x + a.y * bb.y + a.z * bb.z + a.w * bb.w;
    }

    // ---- match state ----
    const int di = down_idx[item];
    const int allowed = conn[(size_t)di * C_ + lane];   // lane c holds slot c
    const bool valid  = allowed >= 0;
    const int   myup  = up_idx[b * K_ + (lane & 31)];
    const float myval = up_vals[b * K_ + (lane & 31)];
    const float* drow = down_enc + (size_t)di * D_;

    #pragma unroll 1
    for (int j = 0; j < K_; ++j) {
        int tgt = __shfl(myup, j);
        unsigned long long m = __ballot(valid && (allowed == tgt));
        if (m != 0) {   // wave-uniform branch, taken by ~8% of (item,j)
            float w = (float)__popcll(m) * __shfl(myval, j);
            float partial = 0.f;
            #pragma unroll
            for (int ii = 0; ii < 12; ++ii) {
                int d = lane + 64 * ii;
                partial += drow[d] * up_dec[(size_t)d * DICT_ + tgt];
            }
            acc += w * partial;
        }
    }

    #pragma unroll
    for (int off = 32; off; off >>= 1) acc += __shfl_xor(acc, off);
    if (lane == 0) out[item] = acc;
}

extern "C" void kernel_launch(void* const* d_in, const int* in_sizes, int n_in,
                              void* d_out, int out_size, void* d_ws, size_t ws_size,
                              hipStream_t stream) {
    (void)in_sizes; (void)n_in; (void)out_size; (void)d_ws; (void)ws_size;
    const float* up_vals  = (const float*)d_in[0];
    const float* up_dec   = (const float*)d_in[1];
    const float* down_enc = (const float*)d_in[2];
    const float* up_enc   = (const float*)d_in[3];
    const float* b_dec    = (const float*)d_in[4];
    const int*   up_idx   = (const int*)d_in[5];
    const int*   down_idx = (const int*)d_in[6];
    const int*   conn     = (const int*)d_in[7];
    float* out = (float*)d_out;

    scae_fused_kernel<<<(B_ * K_) / 4, 256, 0, stream>>>(
        up_vals, up_dec, down_enc, up_enc, b_dec, up_idx, down_idx, conn, out);
}